// Round 1
// baseline (1434.681 us; speedup 1.0000x reference)
//
#include <hip/hip_runtime.h>
#include <math.h>

// BiometricLSTM: 2-layer LSTM, B=512, T=2048, I=3, H=64, fp32 in/out. Output = final h2 (B,64).
//
// R18: R17 (best, 1341.8 us) with three serial-chain cuts; structure untouched.
// The kernel is latency-bound at ~1500 cy/iter; per-iter chain =
// barrier -> ds_read a-frags -> MFMA pair -> sel4 -> xproj -> activations -> ds_write.
//  (1) Activations used plain f32 divides -> hipcc emits the IEEE
//      v_div_scale/v_div_fmas/v_div_fixup expansion (~7 serial ops each, 5 divs/step,
//      2 on the recurrence chain). Replace with __builtin_amdgcn_rcpf (1 ulp; h and
//      weights are already f16-quantized so this is noise).
//  (2) Fold x-projection into the MFMA C-init: Cinit[c] = bias[c] + Wx.x[t] for all
//      4 seqs (48 independent FMAs), computed inside the ds_read latency window.
//      Post-MFMA path becomes sel4 -> activation (was sel4 -> 3 dep FMAs -> act).
//      Each L0 lane now prefetches x triples of all 4 seqs (wave-uniform, cached).
//  (3) Split the z-chained recurrence MFMA pair into two parallel accumulators
//      (C-init in acc0, zero in acc1, f32x4 add after) for L0 gates and L1 gates:
//      saves one MFMA dep-latency. accP (pI, off-critical) stays z-chained.
// All else R17 verbatim: 128 blocks x 512 thr, split waves (L0 = Whh0+Wih1 16 MFMA,
// L1 = Whh1 8 MFMA, lag 2), M=4 replicated rows, quad-selected in-lane update,
// HSTR=80 (0 conflicts), ONE barrier/iter, f16 weights/h + f32 accum.
// Parities verified unchanged: h1[t]@t&1; h2[t]@t&1; pIbuf write@prev / read@cur.

typedef _Float16 half8 __attribute__((ext_vector_type(8)));
typedef float    f32x4 __attribute__((ext_vector_type(4)));

constexpr int TT = 2048;
constexpr int HSTR = 80;   // h row stride in halves (160 B)

__device__ __forceinline__ float fast_sigmoid(float x) {
    // 1/(1+e^-x) with single v_rcp (no IEEE div expansion)
    return __builtin_amdgcn_rcpf(1.0f + __expf(-x));
}
// tanh = 1 - 2/(exp(2x)+1): saturates correctly at +-inf
__device__ __forceinline__ float fast_tanh(float x) {
    return 1.0f - 2.0f * __builtin_amdgcn_rcpf(__expf(2.0f * x) + 1.0f);
}
// select component q (lane's quad) from an f32x4 accumulator
__device__ __forceinline__ float sel4(f32x4 v, int q) {
    float r = v[0];
    r = (q == 1) ? v[1] : r;
    r = (q == 2) ? v[2] : r;
    r = (q == 3) ? v[3] : r;
    return r;
}

__global__ __launch_bounds__(512) void lstm2_fused(
    const float* __restrict__ x,
    const float* __restrict__ Wih0, const float* __restrict__ Whh0,
    const float* __restrict__ bih0, const float* __restrict__ bhh0,
    const float* __restrict__ Wih1, const float* __restrict__ Whh1,
    const float* __restrict__ bih1, const float* __restrict__ bhh1,
    float* __restrict__ out)
{
    __shared__ __align__(16) _Float16 h1a[2][4 * HSTR];   // [parity][seq*HSTR + elem]
    __shared__ __align__(16) _Float16 h2a[2][4 * HSTR];
    __shared__ __align__(16) float4   pIbuf[2][4][64];    // [stepParity][class][col] = 4 seqs

    const int tid  = threadIdx.x;
    const int lane = tid & 63;
    const int wid  = tid >> 6;
    const int quad = lane >> 4;
    const int l16  = lane & 15;
    const bool isL1 = (wid >= 4);
    const int col  = (wid & 3) * 16 + l16;   // gate-elem column this lane owns per class

    // ---- zero h double-buffers ----
    for (int i = tid; i < 2 * 4 * HSTR; i += 512) {
        ((_Float16*)h1a)[i] = (_Float16)0.0f;
        ((_Float16*)h2a)[i] = (_Float16)0.0f;
    }

    // ---- weights (B-frags, f16): lane holds W[c*64+col][f*32 + quad*8 .. +8] ----
    half8 wA[4][2];      // L0 waves: Whh0 | L1 waves: Whh1
    half8 wB[4][2];      // L0 waves only: Wih1
    f32x4 cbias[4];      // bias splat, MFMA C-init base (L0: bias0; L1: bias1)
    float wxa[4], wxb[4], wxc[4];            // L0 only
    #pragma unroll
    for (int c = 0; c < 4; ++c) {
        const int row = c * 64 + col;
        if (!isL1) {
            #pragma unroll
            for (int f = 0; f < 2; ++f) {
                const float* p = Whh0 + (size_t)row * 64 + f * 32 + quad * 8;
                half8 h;
                #pragma unroll
                for (int u = 0; u < 8; ++u) h[u] = (_Float16)p[u];
                wA[c][f] = h;
                const float* q = Wih1 + (size_t)row * 64 + f * 32 + quad * 8;
                half8 g;
                #pragma unroll
                for (int u = 0; u < 8; ++u) g[u] = (_Float16)q[u];
                wB[c][f] = g;
            }
            const float b = bih0[row] + bhh0[row];
            cbias[c] = f32x4{b, b, b, b};
            wxa[c] = Wih0[row*3+0]; wxb[c] = Wih0[row*3+1]; wxc[c] = Wih0[row*3+2];
        } else {
            #pragma unroll
            for (int f = 0; f < 2; ++f) {
                const float* p = Whh1 + (size_t)row * 64 + f * 32 + quad * 8;
                half8 h;
                #pragma unroll
                for (int u = 0; u < 8; ++u) h[u] = (_Float16)p[u];
                wA[c][f] = h;
            }
            const float b = bih1[row] + bhh1[row];
            cbias[c] = f32x4{b, b, b, b};
        }
    }

    // ---- x prefetch (L0 waves): all 4 seqs' triples (wave-uniform, L1-cached) ----
    const float* xb = x + (size_t)blockIdx.x * 4 * TT * 3;
    f32x4 X0 = {0.f,0.f,0.f,0.f}, X1 = X0, X2 = X0;
    if (!isL1) {
        #pragma unroll
        for (int j = 0; j < 4; ++j) {
            const float* p = xb + (size_t)j * TT * 3;
            X0[j] = p[0]; X1[j] = p[1]; X2[j] = p[2];
        }
    }

    const f32x4 Z = {0.f, 0.f, 0.f, 0.f};
    float cst = 0.0f;    // cell state (layer per role, seq=quad, elem=col)

    __syncthreads();

    // iter it = 0 .. TT+1. L0: step it (it<TT) + pI(it-1) (it<=TT).
    // L1: step it-2 (it>=2). ONE barrier per iteration.
    for (int it = 0; it <= TT + 1; ++it) {
        const int cur  = it & 1;
        const int prev = cur ^ 1;

        if (!isL1) {
            if (it <= TT) {
                // A-frags: h1[it-1] (parity prev), replicated rows — issue reads first
                const _Float16* hb = h1a[prev] + (l16 & 3) * HSTR + quad * 8;
                half8 a0 = *(const half8*)hb;
                half8 a1 = *(const half8*)(hb + 32);

                f32x4 acc0[4], acc1[4];
                const bool doGate = (it < TT);
                if (doGate) {
                    // C-init = bias + Wx.x[it] for all 4 seqs (hides under ds_read)
                    f32x4 ci[4];
                    #pragma unroll
                    for (int c = 0; c < 4; ++c) {
                        f32x4 t = cbias[c];
                        #pragma unroll
                        for (int j = 0; j < 4; ++j)
                            t[j] = fmaf(wxa[c], X0[j],
                                   fmaf(wxb[c], X1[j],
                                   fmaf(wxc[c], X2[j], t[j])));
                        ci[c] = t;
                    }
                    // prefetch x[it+1] (clamped; consumed only if doGate next iter)
                    const int nt = (it + 1 < TT) ? it + 1 : TT - 1;
                    #pragma unroll
                    for (int j = 0; j < 4; ++j) {
                        const float* p = xb + (size_t)j * TT * 3 + (size_t)nt * 3;
                        X0[j] = p[0]; X1[j] = p[1]; X2[j] = p[2];
                    }
                    // L0 gates: Whh0 . h1[it-1] — split accumulators (parallel MFMAs)
                    #pragma unroll
                    for (int c = 0; c < 4; ++c) {
                        acc0[c] = __builtin_amdgcn_mfma_f32_16x16x32_f16(a0, wA[c][0], ci[c], 0, 0, 0);
                        acc1[c] = __builtin_amdgcn_mfma_f32_16x16x32_f16(a1, wA[c][1], Z,     0, 0, 0);
                    }
                }

                // pI(it-1) = Wih1 . h1[it-1]  -> pIbuf[(it-1)&1] == [prev]  (off-critical)
                f32x4 accP[4];
                #pragma unroll
                for (int c = 0; c < 4; ++c) {
                    f32x4 z = Z;
                    z = __builtin_amdgcn_mfma_f32_16x16x32_f16(a0, wB[c][0], z, 0, 0, 0);
                    z = __builtin_amdgcn_mfma_f32_16x16x32_f16(a1, wB[c][1], z, 0, 0, 0);
                    accP[c] = z;
                }
                if (quad == 0) {
                    #pragma unroll
                    for (int c = 0; c < 4; ++c)
                        pIbuf[prev][c][col] = make_float4(accP[c][0], accP[c][1],
                                                          accP[c][2], accP[c][3]);
                }

                if (doGate) {
                    f32x4 g0 = acc0[0] + acc1[0];
                    f32x4 g1 = acc0[1] + acc1[1];
                    f32x4 g2 = acc0[2] + acc1[2];
                    f32x4 g3 = acc0[3] + acc1[3];
                    float pi = sel4(g0, quad);
                    float pf = sel4(g1, quad);
                    float pg = sel4(g2, quad);
                    float po = sel4(g3, quad);
                    float iv = fast_sigmoid(pi), fv = fast_sigmoid(pf);
                    float gv = fast_tanh(pg),    ov = fast_sigmoid(po);
                    cst = fmaf(fv, cst, iv * gv);
                    h1a[cur][quad * HSTR + col] = (_Float16)(ov * fast_tanh(cst)); // h1[it]
                }
            }
        } else {
            if (it >= 2) {
                // L1 step s = it-2: Whh1 . h2[it-3] (parity prev) + pI(s) (pIbuf[cur])
                const _Float16* hb2 = h2a[prev] + (l16 & 3) * HSTR + quad * 8;
                half8 a2 = *(const half8*)hb2;
                half8 a3 = *(const half8*)(hb2 + 32);
                // partial reads issue early; arrive under the MFMA latency
                const float* pb = (const float*)&pIbuf[cur][0][col] + quad;
                f32x4 acc0[4], acc1[4];
                #pragma unroll
                for (int c = 0; c < 4; ++c) {
                    acc0[c] = __builtin_amdgcn_mfma_f32_16x16x32_f16(a2, wA[c][0], cbias[c], 0, 0, 0);
                    acc1[c] = __builtin_amdgcn_mfma_f32_16x16x32_f16(a3, wA[c][1], Z,        0, 0, 0);
                }
                f32x4 g0 = acc0[0] + acc1[0];
                f32x4 g1 = acc0[1] + acc1[1];
                f32x4 g2 = acc0[2] + acc1[2];
                f32x4 g3 = acc0[3] + acc1[3];
                float pi = sel4(g0, quad) + pb[0 * 256];
                float pf = sel4(g1, quad) + pb[1 * 256];
                float pg = sel4(g2, quad) + pb[2 * 256];
                float po = sel4(g3, quad) + pb[3 * 256];
                float iv = fast_sigmoid(pi), fv = fast_sigmoid(pf);
                float gv = fast_tanh(pg),    ov = fast_sigmoid(po);
                cst = fmaf(fv, cst, iv * gv);
                float hv = ov * fast_tanh(cst);
                h2a[cur][quad * HSTR + col] = (_Float16)hv;            // h2[it-2]
                if (it == TT + 1)
                    out[(size_t)(blockIdx.x * 4 + quad) * 64 + col] = hv;
            }
        }
        __syncthreads();
    }
}

extern "C" void kernel_launch(void* const* d_in, const int* in_sizes, int n_in,
                              void* d_out, int out_size, void* d_ws, size_t ws_size,
                              hipStream_t stream) {
    const float* x    = (const float*)d_in[0];
    const float* Wih0 = (const float*)d_in[1];
    const float* Whh0 = (const float*)d_in[2];
    const float* bih0 = (const float*)d_in[3];
    const float* bhh0 = (const float*)d_in[4];
    const float* Wih1 = (const float*)d_in[5];
    const float* Whh1 = (const float*)d_in[6];
    const float* bih1 = (const float*)d_in[7];
    const float* bhh1 = (const float*)d_in[8];
    float* out = (float*)d_out;

    // 512 sequences / 4 per block = 128 blocks; 512 threads (8 waves, 2/SIMD).
    lstm2_fused<<<128, 512, 0, stream>>>(x, Wih0, Whh0, bih0, bhh0,
                                         Wih1, Whh1, bih1, bhh1, out);
}

// Round 2
// 1162.533 us; speedup vs baseline: 1.2341x; 1.2341x over previous
//
#include <hip/hip_runtime.h>
#include <math.h>

// BiometricLSTM: 2-layer LSTM, B=512, T=2048, I=3, H=64, fp32 in/out. Output = final h2 (B,64).
//
// R19: revert to R17 (best, 1341.8 us) + ONLY the two zero-cost chain cuts.
// R18 post-mortem: bundling the C-init x-proj fold + split accumulators raised
// VGPR 68->116 and added 48 FMAs + 12 redundant loads of issue ahead of the gate
// MFMAs -> +7% regression. The structure is latency-bound (~1500cy/iter chain:
// barrier -> ds_read -> MFMA pair -> sel4 -> activations -> ds_write -> barrier),
// so only pure dependency-chain cuts with no added issue/registers qualify:
//  (1) Activations: plain f32 divide compiles to the IEEE v_div_scale/v_div_fmas/
//      v_div_fixup expansion (~7 serial ops each; 5 divs/step, 2 on the c-state
//      recurrence). Use __builtin_amdgcn_rcpf (1 op, 1 ulp — noise vs f16 weights).
//  (2) x-projection hoist: xp[c] = wxa*x0+wxb*x1+wxc*x2 depends only on live regs,
//      so compute BEFORE the MFMAs (hidden under ds_read/MFMA window); post-MFMA
//      becomes a single sel4 + xp[c] add (was 3 dependent adds). Same op count,
//      same registers — pure reorder of R17's own arithmetic.
// All else R17 verbatim: 128 blocks x 512 thr, split waves (L0 = Whh0+Wih1 16 MFMA,
// L1 = Whh1 8 MFMA, lag 2), M=4 replicated rows, quad-selected in-lane update,
// HSTR=80, z-chained MFMA pairs with bias in C, per-quad x prefetch (3 loads),
// ONE barrier/iter, f16 weights/h + f32 accum.
// Parities: h1[t]@t&1; h2[t]@t&1 (write h2a[cur]=h2[it-2], read h2a[prev]=h2[it-3]);
// pIbuf double-buffered by step parity, write@prev / read@cur disjoint.

typedef _Float16 half8 __attribute__((ext_vector_type(8)));
typedef float    f32x4 __attribute__((ext_vector_type(4)));

constexpr int TT = 2048;
constexpr int HSTR = 80;   // h row stride in halves (160 B)

__device__ __forceinline__ float fast_sigmoid(float x) {
    // 1/(1+e^-x) with single v_rcp (no IEEE div expansion)
    return __builtin_amdgcn_rcpf(1.0f + __expf(-x));
}
// tanh = 1 - 2/(exp(2x)+1): saturates correctly at +-inf
__device__ __forceinline__ float fast_tanh(float x) {
    return 1.0f - 2.0f * __builtin_amdgcn_rcpf(__expf(2.0f * x) + 1.0f);
}
// select component q (lane's quad) from an f32x4 accumulator
__device__ __forceinline__ float sel4(f32x4 v, int q) {
    float r = v[0];
    r = (q == 1) ? v[1] : r;
    r = (q == 2) ? v[2] : r;
    r = (q == 3) ? v[3] : r;
    return r;
}

__global__ __launch_bounds__(512) void lstm2_fused(
    const float* __restrict__ x,
    const float* __restrict__ Wih0, const float* __restrict__ Whh0,
    const float* __restrict__ bih0, const float* __restrict__ bhh0,
    const float* __restrict__ Wih1, const float* __restrict__ Whh1,
    const float* __restrict__ bih1, const float* __restrict__ bhh1,
    float* __restrict__ out)
{
    __shared__ __align__(16) _Float16 h1a[2][4 * HSTR];   // [parity][seq*HSTR + elem]
    __shared__ __align__(16) _Float16 h2a[2][4 * HSTR];
    __shared__ __align__(16) float4   pIbuf[2][4][64];    // [stepParity][class][col] = 4 seqs

    const int tid  = threadIdx.x;
    const int lane = tid & 63;
    const int wid  = tid >> 6;
    const int quad = lane >> 4;
    const int l16  = lane & 15;
    const bool isL1 = (wid >= 4);
    const int col  = (wid & 3) * 16 + l16;   // gate-elem column this lane owns per class

    // ---- zero h double-buffers ----
    for (int i = tid; i < 2 * 4 * HSTR; i += 512) {
        ((_Float16*)h1a)[i] = (_Float16)0.0f;
        ((_Float16*)h2a)[i] = (_Float16)0.0f;
    }

    // ---- weights (B-frags, f16): lane holds W[c*64+col][f*32 + quad*8 .. +8] ----
    half8 wA[4][2];      // L0 waves: Whh0 | L1 waves: Whh1
    half8 wB[4][2];      // L0 waves only: Wih1
    f32x4 cbias[4];      // bias splat, MFMA C-init (L0: bias0; L1: bias1)
    float wxa[4], wxb[4], wxc[4];            // L0 only
    #pragma unroll
    for (int c = 0; c < 4; ++c) {
        const int row = c * 64 + col;
        if (!isL1) {
            #pragma unroll
            for (int f = 0; f < 2; ++f) {
                const float* p = Whh0 + (size_t)row * 64 + f * 32 + quad * 8;
                half8 h;
                #pragma unroll
                for (int u = 0; u < 8; ++u) h[u] = (_Float16)p[u];
                wA[c][f] = h;
                const float* q = Wih1 + (size_t)row * 64 + f * 32 + quad * 8;
                half8 g;
                #pragma unroll
                for (int u = 0; u < 8; ++u) g[u] = (_Float16)q[u];
                wB[c][f] = g;
            }
            const float b = bih0[row] + bhh0[row];
            cbias[c] = f32x4{b, b, b, b};
            wxa[c] = Wih0[row*3+0]; wxb[c] = Wih0[row*3+1]; wxc[c] = Wih0[row*3+2];
        } else {
            #pragma unroll
            for (int f = 0; f < 2; ++f) {
                const float* p = Whh1 + (size_t)row * 64 + f * 32 + quad * 8;
                half8 h;
                #pragma unroll
                for (int u = 0; u < 8; ++u) h[u] = (_Float16)p[u];
                wA[c][f] = h;
            }
            const float b = bih1[row] + bhh1[row];
            cbias[c] = f32x4{b, b, b, b};
        }
    }

    // ---- x prefetch (L0 waves): this lane's seq = quad ----
    const float* xq = x + (size_t)(blockIdx.x * 4 + quad) * TT * 3;
    float xn0 = 0.f, xn1 = 0.f, xn2 = 0.f;
    if (!isL1) { xn0 = xq[0]; xn1 = xq[1]; xn2 = xq[2]; }

    float cst = 0.0f;    // cell state (layer per role, seq=quad, elem=col)

    __syncthreads();

    // iter it = 0 .. TT+1. L0: step it (it<TT) + pI(it-1) (it<=TT).
    // L1: step it-2 (it>=2). ONE barrier per iteration.
    for (int it = 0; it <= TT + 1; ++it) {
        const int cur  = it & 1;
        const int prev = cur ^ 1;

        if (!isL1) {
            if (it <= TT) {
                // A-frags: h1[it-1] (parity prev), replicated rows
                const _Float16* hb = h1a[prev] + (l16 & 3) * HSTR + quad * 8;
                half8 a0 = *(const half8*)hb;
                half8 a1 = *(const half8*)(hb + 32);

                // pI(it-1) = Wih1 . h1[it-1]  -> pIbuf[(it-1)&1] == [prev]
                f32x4 accP[4];
                #pragma unroll
                for (int c = 0; c < 4; ++c) {
                    f32x4 z = {0.f, 0.f, 0.f, 0.f};
                    z = __builtin_amdgcn_mfma_f32_16x16x32_f16(a0, wB[c][0], z, 0, 0, 0);
                    z = __builtin_amdgcn_mfma_f32_16x16x32_f16(a1, wB[c][1], z, 0, 0, 0);
                    accP[c] = z;
                }
                if (quad == 0) {
                    #pragma unroll
                    for (int c = 0; c < 4; ++c)
                        pIbuf[prev][c][col] = make_float4(accP[c][0], accP[c][1],
                                                          accP[c][2], accP[c][3]);
                }

                if (it < TT) {
                    // x-projection for this step: independent of MFMA results,
                    // issued before them (hidden under ds_read/MFMA latency).
                    const float x0 = xn0, x1 = xn1, x2 = xn2;
                    float xp0 = fmaf(wxa[0], x0, fmaf(wxb[0], x1, wxc[0] * x2));
                    float xp1 = fmaf(wxa[1], x0, fmaf(wxb[1], x1, wxc[1] * x2));
                    float xp2 = fmaf(wxa[2], x0, fmaf(wxb[2], x1, wxc[2] * x2));
                    float xp3 = fmaf(wxa[3], x0, fmaf(wxb[3], x1, wxc[3] * x2));
                    const int nt = (it + 1 < TT) ? it + 1 : TT - 1;
                    const float* np = xq + nt * 3;
                    xn0 = np[0]; xn1 = np[1]; xn2 = np[2];

                    // L0 gates: Whh0 . h1[it-1] + bias (in C)
                    f32x4 acc[4];
                    #pragma unroll
                    for (int c = 0; c < 4; ++c) {
                        f32x4 z = cbias[c];
                        z = __builtin_amdgcn_mfma_f32_16x16x32_f16(a0, wA[c][0], z, 0, 0, 0);
                        z = __builtin_amdgcn_mfma_f32_16x16x32_f16(a1, wA[c][1], z, 0, 0, 0);
                        acc[c] = z;
                    }
                    float pi = sel4(acc[0], quad) + xp0;
                    float pf = sel4(acc[1], quad) + xp1;
                    float pg = sel4(acc[2], quad) + xp2;
                    float po = sel4(acc[3], quad) + xp3;
                    float iv = fast_sigmoid(pi), fv = fast_sigmoid(pf);
                    float gv = fast_tanh(pg),    ov = fast_sigmoid(po);
                    cst = fmaf(fv, cst, iv * gv);
                    h1a[cur][quad * HSTR + col] = (_Float16)(ov * fast_tanh(cst)); // h1[it]
                }
            }
        } else {
            if (it >= 2) {
                // L1 step s = it-2: Whh1 . h2[it-3] (parity prev) + pI(s) (pIbuf[cur])
                const _Float16* hb2 = h2a[prev] + (l16 & 3) * HSTR + quad * 8;
                half8 a2 = *(const half8*)hb2;
                half8 a3 = *(const half8*)(hb2 + 32);
                f32x4 acc[4];
                #pragma unroll
                for (int c = 0; c < 4; ++c) {
                    f32x4 z = cbias[c];
                    z = __builtin_amdgcn_mfma_f32_16x16x32_f16(a2, wA[c][0], z, 0, 0, 0);
                    z = __builtin_amdgcn_mfma_f32_16x16x32_f16(a3, wA[c][1], z, 0, 0, 0);
                    acc[c] = z;
                }
                // partial: pIbuf[cur][c][col][seq=quad]  (contiguous b32, <=2-way banks)
                const float* pb = (const float*)&pIbuf[cur][0][col] + quad;
                float pi = sel4(acc[0], quad) + pb[0 * 256];
                float pf = sel4(acc[1], quad) + pb[1 * 256];
                float pg = sel4(acc[2], quad) + pb[2 * 256];
                float po = sel4(acc[3], quad) + pb[3 * 256];
                float iv = fast_sigmoid(pi), fv = fast_sigmoid(pf);
                float gv = fast_tanh(pg),    ov = fast_sigmoid(po);
                cst = fmaf(fv, cst, iv * gv);
                float hv = ov * fast_tanh(cst);
                h2a[cur][quad * HSTR + col] = (_Float16)hv;            // h2[it-2]
                if (it == TT + 1)
                    out[(size_t)(blockIdx.x * 4 + quad) * 64 + col] = hv;
            }
        }
        __syncthreads();
    }
}

extern "C" void kernel_launch(void* const* d_in, const int* in_sizes, int n_in,
                              void* d_out, int out_size, void* d_ws, size_t ws_size,
                              hipStream_t stream) {
    const float* x    = (const float*)d_in[0];
    const float* Wih0 = (const float*)d_in[1];
    const float* Whh0 = (const float*)d_in[2];
    const float* bih0 = (const float*)d_in[3];
    const float* bhh0 = (const float*)d_in[4];
    const float* Wih1 = (const float*)d_in[5];
    const float* Whh1 = (const float*)d_in[6];
    const float* bih1 = (const float*)d_in[7];
    const float* bhh1 = (const float*)d_in[8];
    float* out = (float*)d_out;

    // 512 sequences / 4 per block = 128 blocks; 512 threads (8 waves, 2/SIMD).
    lstm2_fused<<<128, 512, 0, stream>>>(x, Wih0, Whh0, bih0, bhh0,
                                         Wih1, Whh1, bih1, bhh1, out);
}

// Round 5
// 1064.070 us; speedup vs baseline: 1.3483x; 1.0925x over previous
//
#include <hip/hip_runtime.h>
#include <math.h>

// BiometricLSTM: 2-layer LSTM, B=512, T=2048, I=3, H=64, fp32 in/out. Output = final h2 (B,64).
//
// R22 == R20 resubmitted verbatim (second GPUAcquisitionTimeout; the
// issue-order hypothesis is still unmeasured — do not stack changes).
//
// R20: R19 (best, 1162.5 us) + issue-order fixes only. No arithmetic change.
//  (1) Gates-before-pI reorder (L0): MFMA issue is in-order per wave; R19 issued
//      8 pI MFMAs (deadline = next iteration) AHEAD of the 8 gate MFMAs (critical
//      h1-recurrence). Reorder so gates issue right after the a-frag ds_reads;
//      pI MFMAs then fill the MFMA pipe while the VALU activation tail runs.
//      Cuts ~50-64cy of in-order issue delay off the recurrence path.
//  (2) Unroll-by-2: iterate pairs (it, it+1) with an unrolled sub-loop so
//      cur/prev are compile-time constants — kills per-iter parity address math
//      and loop overhead.
//  (3) L1: hoist the 4 pIbuf ds_reads ahead of the MFMA chain (same fix as (1);
//      data is one-barrier old, always valid at body start).
// All else R19 verbatim: 128 blocks x 512 thr, split waves (L0 = Whh0+Wih1
// 16 MFMA, L1 = Whh1 8 MFMA, lag 2), M=4 replicated rows, quad-selected in-lane
// update, HSTR=80, z-chained MFMA pairs with bias in C, rcp-based activations,
// x-projection hoisted pre-MFMA, ONE barrier/iter, f16 weights/h + f32 accum.
// Parities: h1[t]@t&1; h2[t]@t&1; pIbuf write@prev / read@cur disjoint.

typedef _Float16 half8 __attribute__((ext_vector_type(8)));
typedef float    f32x4 __attribute__((ext_vector_type(4)));

constexpr int TT = 2048;
constexpr int HSTR = 80;   // h row stride in halves (160 B)

__device__ __forceinline__ float fast_sigmoid(float x) {
    // 1/(1+e^-x) with single v_rcp (no IEEE div expansion)
    return __builtin_amdgcn_rcpf(1.0f + __expf(-x));
}
// tanh = 1 - 2/(exp(2x)+1): saturates correctly at +-inf
__device__ __forceinline__ float fast_tanh(float x) {
    return 1.0f - 2.0f * __builtin_amdgcn_rcpf(__expf(2.0f * x) + 1.0f);
}
// select component q (lane's quad) from an f32x4 accumulator
__device__ __forceinline__ float sel4(f32x4 v, int q) {
    float r = v[0];
    r = (q == 1) ? v[1] : r;
    r = (q == 2) ? v[2] : r;
    r = (q == 3) ? v[3] : r;
    return r;
}

__global__ __launch_bounds__(512) void lstm2_fused(
    const float* __restrict__ x,
    const float* __restrict__ Wih0, const float* __restrict__ Whh0,
    const float* __restrict__ bih0, const float* __restrict__ bhh0,
    const float* __restrict__ Wih1, const float* __restrict__ Whh1,
    const float* __restrict__ bih1, const float* __restrict__ bhh1,
    float* __restrict__ out)
{
    __shared__ __align__(16) _Float16 h1a[2][4 * HSTR];   // [parity][seq*HSTR + elem]
    __shared__ __align__(16) _Float16 h2a[2][4 * HSTR];
    __shared__ __align__(16) float4   pIbuf[2][4][64];    // [stepParity][class][col] = 4 seqs

    const int tid  = threadIdx.x;
    const int lane = tid & 63;
    const int wid  = tid >> 6;
    const int quad = lane >> 4;
    const int l16  = lane & 15;
    const bool isL1 = (wid >= 4);
    const int col  = (wid & 3) * 16 + l16;   // gate-elem column this lane owns per class

    // ---- zero h double-buffers ----
    for (int i = tid; i < 2 * 4 * HSTR; i += 512) {
        ((_Float16*)h1a)[i] = (_Float16)0.0f;
        ((_Float16*)h2a)[i] = (_Float16)0.0f;
    }

    // ---- weights (B-frags, f16): lane holds W[c*64+col][f*32 + quad*8 .. +8] ----
    half8 wA[4][2];      // L0 waves: Whh0 | L1 waves: Whh1
    half8 wB[4][2];      // L0 waves only: Wih1
    f32x4 cbias[4];      // bias splat, MFMA C-init (L0: bias0; L1: bias1)
    float wxa[4], wxb[4], wxc[4];            // L0 only
    #pragma unroll
    for (int c = 0; c < 4; ++c) {
        const int row = c * 64 + col;
        if (!isL1) {
            #pragma unroll
            for (int f = 0; f < 2; ++f) {
                const float* p = Whh0 + (size_t)row * 64 + f * 32 + quad * 8;
                half8 h;
                #pragma unroll
                for (int u = 0; u < 8; ++u) h[u] = (_Float16)p[u];
                wA[c][f] = h;
                const float* q = Wih1 + (size_t)row * 64 + f * 32 + quad * 8;
                half8 g;
                #pragma unroll
                for (int u = 0; u < 8; ++u) g[u] = (_Float16)q[u];
                wB[c][f] = g;
            }
            const float b = bih0[row] + bhh0[row];
            cbias[c] = f32x4{b, b, b, b};
            wxa[c] = Wih0[row*3+0]; wxb[c] = Wih0[row*3+1]; wxc[c] = Wih0[row*3+2];
        } else {
            #pragma unroll
            for (int f = 0; f < 2; ++f) {
                const float* p = Whh1 + (size_t)row * 64 + f * 32 + quad * 8;
                half8 h;
                #pragma unroll
                for (int u = 0; u < 8; ++u) h[u] = (_Float16)p[u];
                wA[c][f] = h;
            }
            const float b = bih1[row] + bhh1[row];
            cbias[c] = f32x4{b, b, b, b};
        }
    }

    // ---- x prefetch (L0 waves): this lane's seq = quad ----
    const float* xq = x + (size_t)(blockIdx.x * 4 + quad) * TT * 3;
    float xn0 = 0.f, xn1 = 0.f, xn2 = 0.f;
    if (!isL1) { xn0 = xq[0]; xn1 = xq[1]; xn2 = xq[2]; }

    float cst = 0.0f;    // cell state (layer per role, seq=quad, elem=col)

    __syncthreads();

    // iter it = 0 .. TT+1 in unrolled pairs (cur/prev compile-time).
    // L0: step it (it<TT) + pI(it-1) (it<=TT).  L1: step it-2 (it>=2).
    // ONE barrier per iteration.
    for (int bt = 0; bt <= TT + 1; bt += 2) {
        #pragma unroll
        for (int sub = 0; sub < 2; ++sub) {
            const int it   = bt + sub;
            const int cur  = sub;        // bt even => it&1 == sub
            const int prev = sub ^ 1;

            if (!isL1) {
                if (it <= TT) {
                    // A-frags: h1[it-1] (parity prev), replicated rows
                    const _Float16* hb = h1a[prev] + (l16 & 3) * HSTR + quad * 8;
                    half8 a0 = *(const half8*)hb;
                    half8 a1 = *(const half8*)(hb + 32);

                    const bool doGate = (it < TT);
                    f32x4 acc[4];
                    float xp0, xp1, xp2, xp3;
                    if (doGate) {
                        // x-projection: independent of MFMA results, hidden
                        // under the ds_read latency window.
                        const float x0 = xn0, x1 = xn1, x2 = xn2;
                        xp0 = fmaf(wxa[0], x0, fmaf(wxb[0], x1, wxc[0] * x2));
                        xp1 = fmaf(wxa[1], x0, fmaf(wxb[1], x1, wxc[1] * x2));
                        xp2 = fmaf(wxa[2], x0, fmaf(wxb[2], x1, wxc[2] * x2));
                        xp3 = fmaf(wxa[3], x0, fmaf(wxb[3], x1, wxc[3] * x2));
                        const int nt = (it + 1 < TT) ? it + 1 : TT - 1;
                        const float* np = xq + nt * 3;
                        xn0 = np[0]; xn1 = np[1]; xn2 = np[2];

                        // CRITICAL: gate MFMAs issue first (in-order MFMA pipe).
                        #pragma unroll
                        for (int c = 0; c < 4; ++c) {
                            f32x4 z = cbias[c];
                            z = __builtin_amdgcn_mfma_f32_16x16x32_f16(a0, wA[c][0], z, 0, 0, 0);
                            z = __builtin_amdgcn_mfma_f32_16x16x32_f16(a1, wA[c][1], z, 0, 0, 0);
                            acc[c] = z;
                        }
                    }

                    // pI(it-1) = Wih1 . h1[it-1] -> pIbuf[prev]; deadline is the
                    // NEXT iteration's L1 read — issues behind gates, completes
                    // under the VALU activation tail.
                    f32x4 accP[4];
                    #pragma unroll
                    for (int c = 0; c < 4; ++c) {
                        f32x4 z = {0.f, 0.f, 0.f, 0.f};
                        z = __builtin_amdgcn_mfma_f32_16x16x32_f16(a0, wB[c][0], z, 0, 0, 0);
                        z = __builtin_amdgcn_mfma_f32_16x16x32_f16(a1, wB[c][1], z, 0, 0, 0);
                        accP[c] = z;
                    }

                    if (doGate) {
                        float pi = sel4(acc[0], quad) + xp0;
                        float pf = sel4(acc[1], quad) + xp1;
                        float pg = sel4(acc[2], quad) + xp2;
                        float po = sel4(acc[3], quad) + xp3;
                        float iv = fast_sigmoid(pi), fv = fast_sigmoid(pf);
                        float gv = fast_tanh(pg),    ov = fast_sigmoid(po);
                        cst = fmaf(fv, cst, iv * gv);
                        h1a[cur][quad * HSTR + col] = (_Float16)(ov * fast_tanh(cst)); // h1[it]
                    }

                    if (quad == 0) {
                        #pragma unroll
                        for (int c = 0; c < 4; ++c)
                            pIbuf[prev][c][col] = make_float4(accP[c][0], accP[c][1],
                                                              accP[c][2], accP[c][3]);
                    }
                }
            } else {
                if (it >= 2) {
                    // L1 step s = it-2: Whh1 . h2[it-3] (parity prev) + pI(s) (pIbuf[cur])
                    const _Float16* hb2 = h2a[prev] + (l16 & 3) * HSTR + quad * 8;
                    half8 a2 = *(const half8*)hb2;
                    half8 a3 = *(const half8*)(hb2 + 32);
                    // partial sums: hoisted ds_reads (written last iteration,
                    // valid since the barrier; <=2-way banks)
                    const float* pb = (const float*)&pIbuf[cur][0][col] + quad;
                    const float pb0 = pb[0 * 256];
                    const float pb1 = pb[1 * 256];
                    const float pb2 = pb[2 * 256];
                    const float pb3 = pb[3 * 256];
                    f32x4 acc[4];
                    #pragma unroll
                    for (int c = 0; c < 4; ++c) {
                        f32x4 z = cbias[c];
                        z = __builtin_amdgcn_mfma_f32_16x16x32_f16(a2, wA[c][0], z, 0, 0, 0);
                        z = __builtin_amdgcn_mfma_f32_16x16x32_f16(a3, wA[c][1], z, 0, 0, 0);
                        acc[c] = z;
                    }
                    float pi = sel4(acc[0], quad) + pb0;
                    float pf = sel4(acc[1], quad) + pb1;
                    float pg = sel4(acc[2], quad) + pb2;
                    float po = sel4(acc[3], quad) + pb3;
                    float iv = fast_sigmoid(pi), fv = fast_sigmoid(pf);
                    float gv = fast_tanh(pg),    ov = fast_sigmoid(po);
                    cst = fmaf(fv, cst, iv * gv);
                    float hv = ov * fast_tanh(cst);
                    h2a[cur][quad * HSTR + col] = (_Float16)hv;            // h2[it-2]
                    if (it == TT + 1)
                        out[(size_t)(blockIdx.x * 4 + quad) * 64 + col] = hv;
                }
            }
            __syncthreads();
        }
    }
}

extern "C" void kernel_launch(void* const* d_in, const int* in_sizes, int n_in,
                              void* d_out, int out_size, void* d_ws, size_t ws_size,
                              hipStream_t stream) {
    const float* x    = (const float*)d_in[0];
    const float* Wih0 = (const float*)d_in[1];
    const float* Whh0 = (const float*)d_in[2];
    const float* bih0 = (const float*)d_in[3];
    const float* bhh0 = (const float*)d_in[4];
    const float* Wih1 = (const float*)d_in[5];
    const float* Whh1 = (const float*)d_in[6];
    const float* bih1 = (const float*)d_in[7];
    const float* bhh1 = (const float*)d_in[8];
    float* out = (float*)d_out;

    // 512 sequences / 4 per block = 128 blocks; 512 threads (8 waves, 2/SIMD).
    lstm2_fused<<<128, 512, 0, stream>>>(x, Wih0, Whh0, bih0, bhh0,
                                         Wih1, Whh1, bih1, bhh1, out);
}